// Round 9
// baseline (371.589 us; speedup 1.0000x reference)
//
#include <hip/hip_runtime.h>
#include <cmath>

// b=4, c=512, h=w=64 -> n=4096, groups=32 (16 ch/group)
#define NB 4
#define NC 512
#define NN 4096
#define ATTN_SCALE 0.04419417382415922f  // 512^-0.5

typedef __bf16 bf16x8 __attribute__((ext_vector_type(8)));
typedef float floatx4 __attribute__((ext_vector_type(4)));

__device__ __forceinline__ unsigned short f2bf(float f) {
    union { float f; unsigned int u; } v; v.f = f;
    return (unsigned short)((v.u + 0x7fffu + ((v.u >> 16) & 1u)) >> 16);
}
__device__ __forceinline__ unsigned short f2bf_trunc(float f) {
    union { float f; unsigned int u; } v; v.f = f;
    return (unsigned short)(v.u >> 16);
}

__device__ __forceinline__ void gload_lds16(const unsigned short* gp, unsigned short* lp) {
    __builtin_amdgcn_global_load_lds(
        (const __attribute__((address_space(1))) void*)gp,
        (__attribute__((address_space(3))) void*)lp, 16, 0, 0);
}

template<int N> __device__ __forceinline__ void wait_vmcnt() {
    if constexpr (N == 0) asm volatile("s_waitcnt vmcnt(0)" ::: "memory");
    else if constexpr (N == 2) asm volatile("s_waitcnt vmcnt(2)" ::: "memory");
    else if constexpr (N == 3) asm volatile("s_waitcnt vmcnt(3)" ::: "memory");
    else if constexpr (N == 4) asm volatile("s_waitcnt vmcnt(4)" ::: "memory");
    else if constexpr (N == 6) asm volatile("s_waitcnt vmcnt(6)" ::: "memory");
}

// ---------------------------------------------------------------------------
// Kernel 1a: GroupNorm partial sums. 1024 blocks = (b,g) x 8 slices.
// ---------------------------------------------------------------------------
__global__ __launch_bounds__(256) void gn_partial_kernel(
    const float* __restrict__ x, float* __restrict__ part)
{
    int blk = blockIdx.x;
    int bg = blk >> 3, sub = blk & 7;
    const float4* xv = (const float4*)(x + (size_t)bg * 16 * NN + (size_t)sub * 8192);
    float s1 = 0.f, s2 = 0.f;
#pragma unroll
    for (int i = 0; i < 8; ++i) {
        float4 v = xv[threadIdx.x + i * 256];
        s1 += v.x + v.y + v.z + v.w;
        s2 += v.x * v.x + v.y * v.y + v.z * v.z + v.w * v.w;
    }
#pragma unroll
    for (int off = 32; off; off >>= 1) {
        s1 += __shfl_xor(s1, off, 64);
        s2 += __shfl_xor(s2, off, 64);
    }
    __shared__ float r1[4], r2[4];
    int lane = threadIdx.x & 63, w = threadIdx.x >> 6;
    if (lane == 0) { r1[w] = s1; r2[w] = s2; }
    __syncthreads();
    if (threadIdx.x == 0) {
        part[blk * 2]     = r1[0] + r1[1] + r1[2] + r1[3];
        part[blk * 2 + 1] = r2[0] + r2[1] + r2[2] + r2[3];
    }
}

// Kernel 1b: finalize -> per-channel scale/shift
__global__ __launch_bounds__(128) void gn_final_kernel(
    const float* __restrict__ part, const float* __restrict__ gw,
    const float* __restrict__ gb, float* __restrict__ ss)
{
    int tg = threadIdx.x;            // 0..127 = b*32+g
    int b = tg >> 5, g = tg & 31;
    float s1 = 0.f, s2 = 0.f;
#pragma unroll
    for (int s = 0; s < 8; ++s) {
        s1 += part[(tg * 8 + s) * 2];
        s2 += part[(tg * 8 + s) * 2 + 1];
    }
    float mean = s1 * (1.0f / 65536.0f);
    float var  = s2 * (1.0f / 65536.0f) - mean * mean;
    float rstd = rsqrtf(var + 1e-5f);
#pragma unroll
    for (int i = 0; i < 16; ++i) {
        int c = g * 16 + i;
        float sc = rstd * gw[c];
        ss[b * NC + c] = sc;
        ss[2048 + b * NC + c] = gb[c] - mean * sc;
    }
}

// ---------------------------------------------------------------------------
// Kernel 2: convert weights fp32 -> bf16
// ---------------------------------------------------------------------------
__global__ __launch_bounds__(256) void wconv_kernel(
    const float* __restrict__ qkv_w, const float* __restrict__ out_w,
    unsigned short* __restrict__ wq, unsigned short* __restrict__ wo)
{
    int i = blockIdx.x * 256 + threadIdx.x;
    const int NQ = 1536 * 512;
    if (i < NQ) wq[i] = f2bf(qkv_w[i]);
    else        wo[i - NQ] = f2bf(out_w[i - NQ]);
}

// ---------------------------------------------------------------------------
// Kernel 3: normalize + transpose: x (b,c,n) fp32 -> h_t (b,n,c) bf16
// ---------------------------------------------------------------------------
__global__ __launch_bounds__(256) void htnorm_kernel(
    const float* __restrict__ x, const float* __restrict__ ss,
    unsigned short* __restrict__ ht)
{
    int b = blockIdx.z;
    int c0 = blockIdx.y * 32, n0 = blockIdx.x * 32;
    __shared__ float T[32][33];
    int tx = threadIdx.x & 31, ty = threadIdx.x >> 5;   // ty 0..7
    const float* xb = x + ((size_t)b * NC + c0) * NN;
    const float* sc = ss + b * NC + c0;
    const float* sh = ss + 2048 + b * NC + c0;
#pragma unroll
    for (int i = 0; i < 4; ++i) {
        int c = ty + i * 8;
        T[c][tx] = xb[(size_t)c * NN + n0 + tx] * sc[c] + sh[c];
    }
    __syncthreads();
    unsigned short* hb = ht + ((size_t)b * NN + n0) * NC + c0;
#pragma unroll
    for (int i = 0; i < 4; ++i) {
        int n = ty + i * 8;
        hb[(size_t)n * NC + tx] = f2bf(T[tx][n]);
    }
}

// ---------------------------------------------------------------------------
// MFMA NT GEMM: C[m,n] = sum_k A[m,k]*B[n,k], BK=32, KD=512, NBUF=3.
//  PIPE=0: counted-vmcnt loop (r5 structure).
//  PIPE=1: corrected cross-barrier reg pipeline (race-free: barrier after
//   vmcnt orders ALL waves' stage writes before any wave's ds_frags read;
//   ds_frags(next set) co-issues with mfma(cur set) -- proven ~-30us on the
//   projections in r7). Round-9: applied to MODE 2 as well (FI=8: acc 128 +
//   frag sets 96 = ~244 VGPR, fits the 256 cap at launch_bounds(256,2)).
// MODE 0: qkv q/k   M=4096 N=1024 K=512  A=ht(+z) B=wqk    -> qt(*scale)/kt +bias
// MODE 1: qkv v     M=512  N=4096 K=512  A=wv     B=ht(+z) -> vt (c,p) bf16 +bias
// MODE 2: QK^T      M=4096 N=4096 K=512  A=qt(+z) B=kt(+z) -> SP = exp(s) bf16,
//                   row-sums atomically accumulated into outf = L[b*NN+row]
// MODE 4: out proj  M=512  N=4096 K=512  A=wo     B=Ob(+z) -> out fp32 +bias+res
// ---------------------------------------------------------------------------
template<int MODE, int BM, int BN, int KD, int MINB, int PIPE>
__global__ __launch_bounds__(256, MINB) void mfma_gemm(
    const unsigned short* __restrict__ Abase,
    const unsigned short* __restrict__ Bbase,
    const float* __restrict__ e0, const float* __restrict__ e1,
    float* __restrict__ outf,
    unsigned short* __restrict__ ob0, unsigned short* __restrict__ ob1)
{
    constexpr int NT = KD / 32;       // 16 K-steps (even)
    constexpr int FI = BM / 32;       // frag rows per wave
    constexpr int FJ = BN / 32;       // frag cols per wave
    constexpr int LPS = BM / 64 + BN / 64;   // gloads per thread per stage
    const size_t bnc = (size_t)NN * NC;
    const size_t bss = (size_t)NN * NN;

    int z, m0, n0;
    if constexpr (MODE == 2) {
        // XCD-grouped 1-D decode (grid 2048, rr dispatch): each XCD owns 8
        // m-tiles (2MB qt panel L2-resident), n-tile slow.
        const int id = blockIdx.x;
        const int xcd = id & 7, j = id >> 3;       // j in [0,256)
        const int mi = xcd * 8 + (j & 7);          // [0,64)
        z = mi >> 4; m0 = (mi & 15) * BM; n0 = (j >> 3) * BN;
    } else {
        z = blockIdx.z; m0 = blockIdx.y * BM; n0 = blockIdx.x * BN;
    }

    const unsigned short* A;
    const unsigned short* B;
    if constexpr (MODE == 0)      { A = Abase + (size_t)z * bnc; B = Bbase; }
    else if constexpr (MODE == 1) { A = Abase; B = Bbase + (size_t)z * bnc; }
    else if constexpr (MODE == 2) { A = Abase + (size_t)z * bnc; B = Bbase + (size_t)z * bnc; }
    else                          { A = Abase; B = Bbase + (size_t)z * bnc; }

    __shared__ __attribute__((aligned(16))) unsigned short As[3][BM * 32];
    __shared__ __attribute__((aligned(16))) unsigned short Bs[3][BN * 32];

    const int t = threadIdx.x;
    const int lane = t & 63;
    const int w = t >> 6;
    const int wr = w >> 1, wc = w & 1;

    // staging: one gload round = 256 threads x 16B = 64 rows x 32 cols.
    const int sr = w * 16 + (lane >> 2);                    // row in 64-row slab
    const int scs = ((lane & 3) ^ ((lane >> 3) & 3)) * 8;   // pre-swizzled col
    const int lds_elem = w * 512;
    const int kslot = lane >> 4;

    floatx4 acc[FI][FJ] = {};

    auto stage = [&](int buf, int tile) {
        const int k0 = tile * 32;
#pragma unroll
        for (int s = 0; s < BM / 64; ++s)
            gload_lds16(A + (size_t)(m0 + s * 64 + sr) * KD + k0 + scs,
                        &As[buf][s * 2048 + lds_elem]);
#pragma unroll
        for (int s = 0; s < BN / 64; ++s)
            gload_lds16(B + (size_t)(n0 + s * 64 + sr) * KD + k0 + scs,
                        &Bs[buf][s * 2048 + lds_elem]);
    };

    auto ds_frags = [&](int buf, bf16x8* af, bf16x8* bfr) {
#pragma unroll
        for (int i = 0; i < FI; ++i) {
            const int ra = wr * (BM / 2) + i * 16 + (lane & 15);
            af[i] = *(const bf16x8*)(&As[buf][ra * 32 + ((kslot ^ ((ra >> 1) & 3)) * 8)]);
        }
#pragma unroll
        for (int j = 0; j < FJ; ++j) {
            const int rb = wc * (BN / 2) + j * 16 + (lane & 15);
            bfr[j] = *(const bf16x8*)(&Bs[buf][rb * 32 + ((kslot ^ ((rb >> 1) & 3)) * 8)]);
        }
    };

    auto mfma_all = [&](const bf16x8* af, const bf16x8* bfr) {
#pragma unroll
        for (int i = 0; i < FI; ++i)
#pragma unroll
            for (int j = 0; j < FJ; ++j)
                acc[i][j] = __builtin_amdgcn_mfma_f32_16x16x32_bf16(
                    af[i], bfr[j], acc[i][j], 0, 0, 0);
    };

    if constexpr (PIPE == 0) {
        // ---- counted-vmcnt loop (DEPTH=2) ----
        bf16x8 af[FI], bfr[FJ];
        stage(0, 0);
        stage(1, 1);
        wait_vmcnt<LPS>();
        __builtin_amdgcn_s_barrier();
#pragma unroll
        for (int kt = 0; kt < NT - 2; ++kt) {
            stage((kt + 2) % 3, kt + 2);
            ds_frags(kt % 3, af, bfr);
            mfma_all(af, bfr);
            asm volatile("s_waitcnt lgkmcnt(0)" ::: "memory");
            wait_vmcnt<LPS>();
            __builtin_amdgcn_s_barrier();
        }
        ds_frags((NT - 2) % 3, af, bfr);
        mfma_all(af, bfr);
        asm volatile("s_waitcnt lgkmcnt(0)" ::: "memory");
        wait_vmcnt<0>();
        __builtin_amdgcn_s_barrier();
        ds_frags((NT - 1) % 3, af, bfr);
        mfma_all(af, bfr);
    } else {
        // ---- corrected cross-barrier reg pipeline (ping-pong sets) ----
        bf16x8 afA[FI], bfA[FJ], afB[FI], bfB[FJ];
        stage(0, 0);
        stage(1, 1);
        wait_vmcnt<LPS>();                 // tile 0 landed (mine)
        __builtin_amdgcn_s_barrier();      // tile 0 landed (all waves)
        ds_frags(0, afA, bfA);
        asm volatile("s_waitcnt lgkmcnt(0)" ::: "memory");
#pragma unroll
        for (int kp = 0; kp < (NT - 2) / 2; ++kp) {
            const int kt = kp * 2;
            // step kt: compute set A, read tile kt+1 into set B
            stage((kt + 2) % 3, kt + 2);
            wait_vmcnt<LPS>();             // tile kt+1 landed (mine)
            __builtin_amdgcn_s_barrier();  // tile kt+1 landed (all)
            ds_frags((kt + 1) % 3, afB, bfB);
            mfma_all(afA, bfA);
            asm volatile("s_waitcnt lgkmcnt(0)" ::: "memory");
            // step kt+1: compute set B, read tile kt+2 into set A
            stage((kt + 3) % 3, kt + 3);
            wait_vmcnt<LPS>();             // tile kt+2 landed (mine)
            __builtin_amdgcn_s_barrier();  // tile kt+2 landed (all)
            ds_frags((kt + 2) % 3, afA, bfA);
            mfma_all(afB, bfB);
            asm volatile("s_waitcnt lgkmcnt(0)" ::: "memory");
        }
        // tail: steps NT-2 (set A) and NT-1
        wait_vmcnt<0>();                   // tile NT-1 landed (mine)
        __builtin_amdgcn_s_barrier();      // tile NT-1 landed (all)
        ds_frags((NT - 1) % 3, afB, bfB);
        mfma_all(afA, bfA);
        asm volatile("s_waitcnt lgkmcnt(0)" ::: "memory");
        mfma_all(afB, bfB);
    }

    // ---- Epilogue. C/D: col = lane&15, row = (lane>>4)*4 + reg ----
    const int fr = lane >> 4;
    const int fc = lane & 15;

    if constexpr (MODE == 2) {
        // exp + truncated bf16 store + per-row sum (16-lane reduce + atomicAdd)
        float rs[FI][4];
#pragma unroll
        for (int i = 0; i < FI; ++i)
#pragma unroll
            for (int r = 0; r < 4; ++r) rs[i][r] = 0.f;
#pragma unroll
        for (int i = 0; i < FI; ++i) {
#pragma unroll
            for (int j = 0; j < FJ; ++j) {
                int n = n0 + wc * (BN / 2) + j * 16 + fc;
                int mbase = m0 + wr * (BM / 2) + i * 16 + fr * 4;
#pragma unroll
                for (int r = 0; r < 4; ++r) {
                    float e = __expf(acc[i][j][r]);
                    ob0[(size_t)z * bss + (size_t)(mbase + r) * NN + n] = f2bf_trunc(e);
                    rs[i][r] += e;
                }
            }
        }
#pragma unroll
        for (int i = 0; i < FI; ++i) {
#pragma unroll
            for (int r = 0; r < 4; ++r) {
                float v = rs[i][r];
                v += __shfl_xor(v, 1, 16);
                v += __shfl_xor(v, 2, 16);
                v += __shfl_xor(v, 4, 16);
                v += __shfl_xor(v, 8, 16);
                if (fc == 0) {
                    int m = m0 + wr * (BM / 2) + i * 16 + fr * 4 + r;
                    atomicAdd(&outf[z * NN + m], v);
                }
            }
        }
        return;
    }

#pragma unroll
    for (int i = 0; i < FI; ++i) {
#pragma unroll
        for (int j = 0; j < FJ; ++j) {
            int n = n0 + wc * (BN / 2) + j * 16 + fc;
            int mbase = m0 + wr * (BM / 2) + i * 16 + fr * 4;
#pragma unroll
            for (int r = 0; r < 4; ++r) {
                int m = mbase + r;
                float val = acc[i][j][r];
                if constexpr (MODE == 0) {
                    val += e0[n];   // qkv bias, o = n in [0,1024)
                    if (n < 512) ob0[((size_t)z * NN + m) * NC + n] = f2bf(val * ATTN_SCALE);
                    else         ob1[((size_t)z * NN + m) * NC + (n - 512)] = f2bf(val);
                } else if constexpr (MODE == 1) {
                    val += e0[1024 + m];   // v bias, channel = m
                    ob0[((size_t)z * NC + m) * NN + n] = f2bf(val);
                } else {   // MODE 4
                    size_t idx = ((size_t)z * NC + m) * NN + n;
                    outf[idx] = val + e0[m] + e1[idx];
                }
            }
        }
    }
}

// ---------------------------------------------------------------------------
// PV GEMM: O[p,c] = (sum_m P[p,m] * V[m,c]) / L[p]
// Exact r5/r7 version (the best-total round's config): BM=128 x BN=128,
// wave tile 64x64, BK=64 full-line SP rows, dbuf prefetch, 2 blk/CU,
// grid 512, XCD decode. r8's 512-thr/1-blk-CU/NBUF=3 rework REGRESSED
// (~+35us hidden under top-5 cutoff: 1 blk/CU has no co-resident block to
// overlap its barrier/vmcnt waits). Permanently reverted.
// ---------------------------------------------------------------------------
__global__ __launch_bounds__(256, 2) void pv_gemm(
    const unsigned short* __restrict__ Abase,
    const unsigned short* __restrict__ Bbase,
    const float* __restrict__ L,
    unsigned short* __restrict__ Ob)
{
    const int id = blockIdx.x;
    const int xcd = id & 7;
    const int j0 = id >> 3;          // [0,64)
    const int ct = j0 & 3;           // c-tile 0..3 (fastest -> same XCD)
    const int p = (j0 >> 2) * 8 + xcd;   // [0,128) bijective
    const int ptile = p & 31, z = p >> 5;

    const size_t bss = (size_t)NN * NN, bnc = (size_t)NN * NC;
    const unsigned short* A = Abase + (size_t)z * bss;   // SP: (p, m)
    const unsigned short* B = Bbase + (size_t)z * bnc;   // V^T: (c, m)
    const int m0 = ptile * 128;
    const int n0 = ct * 128;

    __shared__ __attribute__((aligned(16))) unsigned short As[2][128 * 64];  // 32 KB
    __shared__ __attribute__((aligned(16))) unsigned short Bs[2][128 * 64];  // 32 KB

    const int t = threadIdx.x;
    const int lane = t & 63;
    const int w = t >> 6;
    const int wr = w >> 1, wc = w & 1;

    // staging: one gload round = 256 threads x 16B = 32 rows x 64 cols.
    const int sr = w * 8 + (lane >> 3);
    const int scs = ((lane & 7) ^ (lane >> 3)) * 8;   // pre-swizzled col (elems)
    const int lds_elem = w * 512;

    floatx4 acc[4][4] = {};

    auto stage = [&](int buf, int k0) {
#pragma unroll
        for (int s = 0; s < 4; ++s)
            gload_lds16(A + (size_t)(m0 + s * 32 + sr) * NN + k0 + scs,
                        &As[buf][s * 2048 + lds_elem]);
#pragma unroll
        for (int s = 0; s < 4; ++s)
            gload_lds16(B + (size_t)(n0 + s * 32 + sr) * NN + k0 + scs,
                        &Bs[buf][s * 2048 + lds_elem]);
    };

    auto compute = [&](int buf) {
#pragma unroll
        for (int kk = 0; kk < 2; ++kk) {
            bf16x8 af[4], bfr[4];
#pragma unroll
            for (int i = 0; i < 4; ++i) {
                const int ra = wr * 64 + i * 16 + (lane & 15);
                af[i] = *(const bf16x8*)(&As[buf][ra * 64 +
                        (((kk * 4 + (lane >> 4)) ^ (ra & 7)) * 8)]);
            }
#pragma unroll
            for (int jf = 0; jf < 4; ++jf) {
                const int rb = wc * 64 + jf * 16 + (lane & 15);
                bfr[jf] = *(const bf16x8*)(&Bs[buf][rb * 64 +
                        (((kk * 4 + (lane >> 4)) ^ (rb & 7)) * 8)]);
            }
#pragma unroll
            for (int i = 0; i < 4; ++i)
#pragma unroll
                for (int jf = 0; jf < 4; ++jf)
                    acc[i][jf] = __builtin_amdgcn_mfma_f32_16x16x32_bf16(
                        af[i], bfr[jf], acc[i][jf], 0, 0, 0);
        }
    };

    stage(0, 0);
    asm volatile("s_waitcnt vmcnt(0)" ::: "memory");
    __builtin_amdgcn_s_barrier();
    for (int kc = 0; kc < 63; ++kc) {
        stage((kc + 1) & 1, (kc + 1) * 64);   // prefetch next chunk (async)
        compute(kc & 1);
        asm volatile("s_waitcnt lgkmcnt(0)" ::: "memory");
        asm volatile("s_waitcnt vmcnt(0)" ::: "memory");
        __builtin_amdgcn_s_barrier();
    }
    compute(1);

    const int fr = lane >> 4;
    const int fc = lane & 15;
#pragma unroll
    for (int i = 0; i < 4; ++i) {
#pragma unroll
        for (int r = 0; r < 4; ++r) {
            int m = m0 + wr * 64 + i * 16 + fr * 4 + r;
            float linv = 1.0f / L[z * NN + m];
#pragma unroll
            for (int jf = 0; jf < 4; ++jf) {
                int n = n0 + wc * 64 + jf * 16 + fc;
                Ob[(size_t)z * bnc + (size_t)m * NC + n] = f2bf(acc[i][jf][r] * linv);
            }
        }
    }
}

// ---------------------------------------------------------------------------
extern "C" void kernel_launch(void* const* d_in, const int* in_sizes, int n_in,
                              void* d_out, int out_size, void* d_ws, size_t ws_size,
                              hipStream_t stream)
{
    const float* x     = (const float*)d_in[0];
    const float* gn_w  = (const float*)d_in[1];
    const float* gn_b  = (const float*)d_in[2];
    const float* qkv_w = (const float*)d_in[3];
    const float* qkv_b = (const float*)d_in[4];
    const float* out_w = (const float*)d_in[5];
    const float* out_b = (const float*)d_in[6];
    float* out = (float*)d_out;

    const size_t bnc = (size_t)NN * NC;          // 2,097,152 per batch
    char* w = (char*)d_ws;
    float* ss   = (float*)w;                 w += 16384;
    float* part = (float*)w;                 w += 8192;
    float* Lsum = (float*)w;                 w += (size_t)NB * NN * 4;  // row sums
    unsigned short* wq = (unsigned short*)w; w += (size_t)1536 * 512 * 2;
    unsigned short* wo = (unsigned short*)w; w += (size_t)512 * 512 * 2;
    unsigned short* qt = (unsigned short*)w; w += NB * bnc * 2;   // (b,n,c) pre-scaled
    unsigned short* kt = (unsigned short*)w; w += NB * bnc * 2;   // (b,n,c)
    unsigned short* vt = (unsigned short*)w; w += NB * bnc * 2;   // (b,c,n)
    unsigned short* SP = (unsigned short*)w; w += (size_t)NB * NN * NN * 2; // 128 MB
    // Aliases (lifetime-disjoint):
    unsigned short* ht = SP;   // ht (b,n,c) dead before MODE 2 writes SP
    unsigned short* Ob = qt;   // Ob (b,n,c) written after qt last read (MODE 2)

    hipMemsetAsync(Lsum, 0, (size_t)NB * NN * sizeof(float), stream);

    gn_partial_kernel<<<1024, 256, 0, stream>>>(x, part);
    gn_final_kernel<<<1, 128, 0, stream>>>(part, gn_w, gn_b, ss);
    wconv_kernel<<<(1536 * 512 + 512 * 512) / 256, 256, 0, stream>>>(qkv_w, out_w, wq, wo);
    htnorm_kernel<<<dim3(NN / 32, NC / 32, NB), 256, 0, stream>>>(x, ss, ht);

    // q/k: C[p,o] = ht · wqk^T   (q pre-scaled by ATTN_SCALE), PIPE=1, 2 blk/CU
    mfma_gemm<0, 128, 128, 512, 2, 1><<<dim3(1024 / 128, NN / 128, NB), 256, 0, stream>>>(
        ht, wq, qkv_b, nullptr, nullptr, qt, kt);
    // v: C[c,p] = wv · ht^T   (64x128 tile, PIPE=1, 4 blk/CU)
    mfma_gemm<1, 64, 128, 512, 4, 1><<<dim3(NN / 128, 512 / 64, NB), 256, 0, stream>>>(
        wq + (size_t)1024 * 512, ht, qkv_b, nullptr, nullptr, vt, nullptr);

    // QK^T + exp + row-sum; BM=256 wave-tile 128x64, PIPE=1 (round-9), XCD-decoded
    mfma_gemm<2, 256, 128, 512, 2, 1><<<dim3(2048), 256, 0, stream>>>(
        qt, kt, nullptr, nullptr, Lsum, SP, nullptr);
    // PV + normalize; r5/r7-exact, 512 blocks, 2 blk/CU, XCD-decoded
    pv_gemm<<<dim3(512), 256, 0, stream>>>(SP, vt, Lsum, Ob);

    // out projection + bias + residual (64x128 tile, PIPE=1, 4 blk/CU)
    mfma_gemm<4, 64, 128, 512, 4, 1><<<dim3(NN / 128, 512 / 64, NB), 256, 0, stream>>>(
        wo, Ob, out_b, x, out, nullptr, nullptr);
}

// Round 10
// 340.351 us; speedup vs baseline: 1.0918x; 1.0918x over previous
//
#include <hip/hip_runtime.h>
#include <cmath>

// b=4, c=512, h=w=64 -> n=4096, groups=32 (16 ch/group)
#define NB 4
#define NC 512
#define NN 4096
#define ATTN_SCALE 0.04419417382415922f  // 512^-0.5

typedef __bf16 bf16x8 __attribute__((ext_vector_type(8)));
typedef float floatx4 __attribute__((ext_vector_type(4)));

__device__ __forceinline__ unsigned short f2bf(float f) {
    union { float f; unsigned int u; } v; v.f = f;
    return (unsigned short)((v.u + 0x7fffu + ((v.u >> 16) & 1u)) >> 16);
}
__device__ __forceinline__ unsigned short f2bf_trunc(float f) {
    union { float f; unsigned int u; } v; v.f = f;
    return (unsigned short)(v.u >> 16);
}

__device__ __forceinline__ void gload_lds16(const unsigned short* gp, unsigned short* lp) {
    __builtin_amdgcn_global_load_lds(
        (const __attribute__((address_space(1))) void*)gp,
        (__attribute__((address_space(3))) void*)lp, 16, 0, 0);
}

template<int N> __device__ __forceinline__ void wait_vmcnt() {
    if constexpr (N == 0) asm volatile("s_waitcnt vmcnt(0)" ::: "memory");
    else if constexpr (N == 2) asm volatile("s_waitcnt vmcnt(2)" ::: "memory");
    else if constexpr (N == 3) asm volatile("s_waitcnt vmcnt(3)" ::: "memory");
    else if constexpr (N == 4) asm volatile("s_waitcnt vmcnt(4)" ::: "memory");
    else if constexpr (N == 6) asm volatile("s_waitcnt vmcnt(6)" ::: "memory");
}

// ---------------------------------------------------------------------------
// Kernel 1a: GroupNorm partial sums. 1024 blocks = (b,g) x 8 slices.
// ---------------------------------------------------------------------------
__global__ __launch_bounds__(256) void gn_partial_kernel(
    const float* __restrict__ x, float* __restrict__ part)
{
    int blk = blockIdx.x;
    int bg = blk >> 3, sub = blk & 7;
    const float4* xv = (const float4*)(x + (size_t)bg * 16 * NN + (size_t)sub * 8192);
    float s1 = 0.f, s2 = 0.f;
#pragma unroll
    for (int i = 0; i < 8; ++i) {
        float4 v = xv[threadIdx.x + i * 256];
        s1 += v.x + v.y + v.z + v.w;
        s2 += v.x * v.x + v.y * v.y + v.z * v.z + v.w * v.w;
    }
#pragma unroll
    for (int off = 32; off; off >>= 1) {
        s1 += __shfl_xor(s1, off, 64);
        s2 += __shfl_xor(s2, off, 64);
    }
    __shared__ float r1[4], r2[4];
    int lane = threadIdx.x & 63, w = threadIdx.x >> 6;
    if (lane == 0) { r1[w] = s1; r2[w] = s2; }
    __syncthreads();
    if (threadIdx.x == 0) {
        part[blk * 2]     = r1[0] + r1[1] + r1[2] + r1[3];
        part[blk * 2 + 1] = r2[0] + r2[1] + r2[2] + r2[3];
    }
}

// Kernel 1b: finalize -> per-channel scale/shift
__global__ __launch_bounds__(128) void gn_final_kernel(
    const float* __restrict__ part, const float* __restrict__ gw,
    const float* __restrict__ gb, float* __restrict__ ss)
{
    int tg = threadIdx.x;            // 0..127 = b*32+g
    int b = tg >> 5, g = tg & 31;
    float s1 = 0.f, s2 = 0.f;
#pragma unroll
    for (int s = 0; s < 8; ++s) {
        s1 += part[(tg * 8 + s) * 2];
        s2 += part[(tg * 8 + s) * 2 + 1];
    }
    float mean = s1 * (1.0f / 65536.0f);
    float var  = s2 * (1.0f / 65536.0f) - mean * mean;
    float rstd = rsqrtf(var + 1e-5f);
#pragma unroll
    for (int i = 0; i < 16; ++i) {
        int c = g * 16 + i;
        float sc = rstd * gw[c];
        ss[b * NC + c] = sc;
        ss[2048 + b * NC + c] = gb[c] - mean * sc;
    }
}

// ---------------------------------------------------------------------------
// Kernel 2: convert weights fp32 -> bf16
// ---------------------------------------------------------------------------
__global__ __launch_bounds__(256) void wconv_kernel(
    const float* __restrict__ qkv_w, const float* __restrict__ out_w,
    unsigned short* __restrict__ wq, unsigned short* __restrict__ wo)
{
    int i = blockIdx.x * 256 + threadIdx.x;
    const int NQ = 1536 * 512;
    if (i < NQ) wq[i] = f2bf(qkv_w[i]);
    else        wo[i - NQ] = f2bf(out_w[i - NQ]);
}

// ---------------------------------------------------------------------------
// Kernel 3: normalize + transpose: x (b,c,n) fp32 -> h_t (b,n,c) bf16
// ---------------------------------------------------------------------------
__global__ __launch_bounds__(256) void htnorm_kernel(
    const float* __restrict__ x, const float* __restrict__ ss,
    unsigned short* __restrict__ ht)
{
    int b = blockIdx.z;
    int c0 = blockIdx.y * 32, n0 = blockIdx.x * 32;
    __shared__ float T[32][33];
    int tx = threadIdx.x & 31, ty = threadIdx.x >> 5;   // ty 0..7
    const float* xb = x + ((size_t)b * NC + c0) * NN;
    const float* sc = ss + b * NC + c0;
    const float* sh = ss + 2048 + b * NC + c0;
#pragma unroll
    for (int i = 0; i < 4; ++i) {
        int c = ty + i * 8;
        T[c][tx] = xb[(size_t)c * NN + n0 + tx] * sc[c] + sh[c];
    }
    __syncthreads();
    unsigned short* hb = ht + ((size_t)b * NN + n0) * NC + c0;
#pragma unroll
    for (int i = 0; i < 4; ++i) {
        int n = ty + i * 8;
        hb[(size_t)n * NC + tx] = f2bf(T[tx][n]);
    }
}

// ---------------------------------------------------------------------------
// MFMA NT GEMM: C[m,n] = sum_k A[m,k]*B[n,k], BK=32, KD=512, NBUF=3.
//  PIPE=0: counted-vmcnt loop. Used by MODE 2 (FI=8: the PIPE=1 two-set
//   pipeline needs ~244 VGPR and SPILLS at the 256 cap -- r9 measured the
//   spill as +43MB FETCH / +87MB WRITE of scratch traffic and +25us. r7/r8
//   measured PIPE=0 at 108-127us. Permanent.)
//  PIPE=1: corrected cross-barrier reg pipeline (race-free: barrier after
//   vmcnt orders ALL waves' stage writes before any wave's ds_frags read;
//   ds_frags(next set) co-issues with mfma(cur set)). Proven ~-30us on the
//   FI<=4 projections (r7). Used by MODES 0/1/4.
// MODE 0: qkv q/k   M=4096 N=1024 K=512  A=ht(+z) B=wqk    -> qt(*scale)/kt +bias
// MODE 1: qkv v     M=512  N=4096 K=512  A=wv     B=ht(+z) -> vt (c,p) bf16 +bias
// MODE 2: QK^T      M=4096 N=4096 K=512  A=qt(+z) B=kt(+z) -> SP = exp(s) bf16,
//                   row-sums atomically accumulated into outf = L[b*NN+row]
// MODE 4: out proj  M=512  N=4096 K=512  A=wo     B=Ob(+z) -> out fp32 +bias+res
// ---------------------------------------------------------------------------
template<int MODE, int BM, int BN, int KD, int MINB, int PIPE>
__global__ __launch_bounds__(256, MINB) void mfma_gemm(
    const unsigned short* __restrict__ Abase,
    const unsigned short* __restrict__ Bbase,
    const float* __restrict__ e0, const float* __restrict__ e1,
    float* __restrict__ outf,
    unsigned short* __restrict__ ob0, unsigned short* __restrict__ ob1)
{
    constexpr int NT = KD / 32;       // 16 K-steps (even)
    constexpr int FI = BM / 32;       // frag rows per wave
    constexpr int FJ = BN / 32;       // frag cols per wave
    constexpr int LPS = BM / 64 + BN / 64;   // gloads per thread per stage
    const size_t bnc = (size_t)NN * NC;
    const size_t bss = (size_t)NN * NN;

    int z, m0, n0;
    if constexpr (MODE == 2) {
        // XCD-grouped 1-D decode (grid 2048, rr dispatch): each XCD owns 8
        // m-tiles (2MB qt panel L2-resident), n-tile slow.
        const int id = blockIdx.x;
        const int xcd = id & 7, j = id >> 3;       // j in [0,256)
        const int mi = xcd * 8 + (j & 7);          // [0,64)
        z = mi >> 4; m0 = (mi & 15) * BM; n0 = (j >> 3) * BN;
    } else {
        z = blockIdx.z; m0 = blockIdx.y * BM; n0 = blockIdx.x * BN;
    }

    const unsigned short* A;
    const unsigned short* B;
    if constexpr (MODE == 0)      { A = Abase + (size_t)z * bnc; B = Bbase; }
    else if constexpr (MODE == 1) { A = Abase; B = Bbase + (size_t)z * bnc; }
    else if constexpr (MODE == 2) { A = Abase + (size_t)z * bnc; B = Bbase + (size_t)z * bnc; }
    else                          { A = Abase; B = Bbase + (size_t)z * bnc; }

    __shared__ __attribute__((aligned(16))) unsigned short As[3][BM * 32];
    __shared__ __attribute__((aligned(16))) unsigned short Bs[3][BN * 32];

    const int t = threadIdx.x;
    const int lane = t & 63;
    const int w = t >> 6;
    const int wr = w >> 1, wc = w & 1;

    // staging: one gload round = 256 threads x 16B = 64 rows x 32 cols.
    const int sr = w * 16 + (lane >> 2);                    // row in 64-row slab
    const int scs = ((lane & 3) ^ ((lane >> 3) & 3)) * 8;   // pre-swizzled col
    const int lds_elem = w * 512;
    const int kslot = lane >> 4;

    floatx4 acc[FI][FJ] = {};

    auto stage = [&](int buf, int tile) {
        const int k0 = tile * 32;
#pragma unroll
        for (int s = 0; s < BM / 64; ++s)
            gload_lds16(A + (size_t)(m0 + s * 64 + sr) * KD + k0 + scs,
                        &As[buf][s * 2048 + lds_elem]);
#pragma unroll
        for (int s = 0; s < BN / 64; ++s)
            gload_lds16(B + (size_t)(n0 + s * 64 + sr) * KD + k0 + scs,
                        &Bs[buf][s * 2048 + lds_elem]);
    };

    auto ds_frags = [&](int buf, bf16x8* af, bf16x8* bfr) {
#pragma unroll
        for (int i = 0; i < FI; ++i) {
            const int ra = wr * (BM / 2) + i * 16 + (lane & 15);
            af[i] = *(const bf16x8*)(&As[buf][ra * 32 + ((kslot ^ ((ra >> 1) & 3)) * 8)]);
        }
#pragma unroll
        for (int j = 0; j < FJ; ++j) {
            const int rb = wc * (BN / 2) + j * 16 + (lane & 15);
            bfr[j] = *(const bf16x8*)(&Bs[buf][rb * 32 + ((kslot ^ ((rb >> 1) & 3)) * 8)]);
        }
    };

    auto mfma_all = [&](const bf16x8* af, const bf16x8* bfr) {
#pragma unroll
        for (int i = 0; i < FI; ++i)
#pragma unroll
            for (int j = 0; j < FJ; ++j)
                acc[i][j] = __builtin_amdgcn_mfma_f32_16x16x32_bf16(
                    af[i], bfr[j], acc[i][j], 0, 0, 0);
    };

    if constexpr (PIPE == 0) {
        // ---- counted-vmcnt loop (DEPTH=2) ----
        bf16x8 af[FI], bfr[FJ];
        stage(0, 0);
        stage(1, 1);
        wait_vmcnt<LPS>();
        __builtin_amdgcn_s_barrier();
#pragma unroll
        for (int kt = 0; kt < NT - 2; ++kt) {
            stage((kt + 2) % 3, kt + 2);
            ds_frags(kt % 3, af, bfr);
            mfma_all(af, bfr);
            asm volatile("s_waitcnt lgkmcnt(0)" ::: "memory");
            wait_vmcnt<LPS>();
            __builtin_amdgcn_s_barrier();
        }
        ds_frags((NT - 2) % 3, af, bfr);
        mfma_all(af, bfr);
        asm volatile("s_waitcnt lgkmcnt(0)" ::: "memory");
        wait_vmcnt<0>();
        __builtin_amdgcn_s_barrier();
        ds_frags((NT - 1) % 3, af, bfr);
        mfma_all(af, bfr);
    } else {
        // ---- corrected cross-barrier reg pipeline (ping-pong sets) ----
        bf16x8 afA[FI], bfA[FJ], afB[FI], bfB[FJ];
        stage(0, 0);
        stage(1, 1);
        wait_vmcnt<LPS>();                 // tile 0 landed (mine)
        __builtin_amdgcn_s_barrier();      // tile 0 landed (all waves)
        ds_frags(0, afA, bfA);
        asm volatile("s_waitcnt lgkmcnt(0)" ::: "memory");
#pragma unroll
        for (int kp = 0; kp < (NT - 2) / 2; ++kp) {
            const int kt = kp * 2;
            // step kt: compute set A, read tile kt+1 into set B
            stage((kt + 2) % 3, kt + 2);
            wait_vmcnt<LPS>();             // tile kt+1 landed (mine)
            __builtin_amdgcn_s_barrier();  // tile kt+1 landed (all)
            ds_frags((kt + 1) % 3, afB, bfB);
            mfma_all(afA, bfA);
            asm volatile("s_waitcnt lgkmcnt(0)" ::: "memory");
            // step kt+1: compute set B, read tile kt+2 into set A
            stage((kt + 3) % 3, kt + 3);
            wait_vmcnt<LPS>();             // tile kt+2 landed (mine)
            __builtin_amdgcn_s_barrier();  // tile kt+2 landed (all)
            ds_frags((kt + 2) % 3, afA, bfA);
            mfma_all(afB, bfB);
            asm volatile("s_waitcnt lgkmcnt(0)" ::: "memory");
        }
        // tail: steps NT-2 (set A) and NT-1
        wait_vmcnt<0>();                   // tile NT-1 landed (mine)
        __builtin_amdgcn_s_barrier();      // tile NT-1 landed (all)
        ds_frags((NT - 1) % 3, afB, bfB);
        mfma_all(afA, bfA);
        asm volatile("s_waitcnt lgkmcnt(0)" ::: "memory");
        mfma_all(afB, bfB);
    }

    // ---- Epilogue. C/D: col = lane&15, row = (lane>>4)*4 + reg ----
    const int fr = lane >> 4;
    const int fc = lane & 15;

    if constexpr (MODE == 2) {
        // exp + truncated bf16 store + per-row sum (16-lane reduce + atomicAdd)
        float rs[FI][4];
#pragma unroll
        for (int i = 0; i < FI; ++i)
#pragma unroll
            for (int r = 0; r < 4; ++r) rs[i][r] = 0.f;
#pragma unroll
        for (int i = 0; i < FI; ++i) {
#pragma unroll
            for (int j = 0; j < FJ; ++j) {
                int n = n0 + wc * (BN / 2) + j * 16 + fc;
                int mbase = m0 + wr * (BM / 2) + i * 16 + fr * 4;
#pragma unroll
                for (int r = 0; r < 4; ++r) {
                    float e = __expf(acc[i][j][r]);
                    ob0[(size_t)z * bss + (size_t)(mbase + r) * NN + n] = f2bf_trunc(e);
                    rs[i][r] += e;
                }
            }
        }
#pragma unroll
        for (int i = 0; i < FI; ++i) {
#pragma unroll
            for (int r = 0; r < 4; ++r) {
                float v = rs[i][r];
                v += __shfl_xor(v, 1, 16);
                v += __shfl_xor(v, 2, 16);
                v += __shfl_xor(v, 4, 16);
                v += __shfl_xor(v, 8, 16);
                if (fc == 0) {
                    int m = m0 + wr * (BM / 2) + i * 16 + fr * 4 + r;
                    atomicAdd(&outf[z * NN + m], v);
                }
            }
        }
        return;
    }

#pragma unroll
    for (int i = 0; i < FI; ++i) {
#pragma unroll
        for (int j = 0; j < FJ; ++j) {
            int n = n0 + wc * (BN / 2) + j * 16 + fc;
            int mbase = m0 + wr * (BM / 2) + i * 16 + fr * 4;
#pragma unroll
            for (int r = 0; r < 4; ++r) {
                int m = mbase + r;
                float val = acc[i][j][r];
                if constexpr (MODE == 0) {
                    val += e0[n];   // qkv bias, o = n in [0,1024)
                    if (n < 512) ob0[((size_t)z * NN + m) * NC + n] = f2bf(val * ATTN_SCALE);
                    else         ob1[((size_t)z * NN + m) * NC + (n - 512)] = f2bf(val);
                } else if constexpr (MODE == 1) {
                    val += e0[1024 + m];   // v bias, channel = m
                    ob0[((size_t)z * NC + m) * NN + n] = f2bf(val);
                } else {   // MODE 4
                    size_t idx = ((size_t)z * NC + m) * NN + n;
                    outf[idx] = val + e0[m] + e1[idx];
                }
            }
        }
    }
}

// ---------------------------------------------------------------------------
// PV GEMM: O[p,c] = (sum_m P[p,m] * V[m,c]) / L[p]
// r5/r7 version: BM=128 x BN=128, wave tile 64x64, BK=64 full-line SP rows,
// dbuf prefetch, 2 blk/CU, grid 512, XCD decode. (r8's 1-blk/CU rework
// regressed ~+35us; permanently reverted.)
// ---------------------------------------------------------------------------
__global__ __launch_bounds__(256, 2) void pv_gemm(
    const unsigned short* __restrict__ Abase,
    const unsigned short* __restrict__ Bbase,
    const float* __restrict__ L,
    unsigned short* __restrict__ Ob)
{
    const int id = blockIdx.x;
    const int xcd = id & 7;
    const int j0 = id >> 3;          // [0,64)
    const int ct = j0 & 3;           // c-tile 0..3 (fastest -> same XCD)
    const int p = (j0 >> 2) * 8 + xcd;   // [0,128) bijective
    const int ptile = p & 31, z = p >> 5;

    const size_t bss = (size_t)NN * NN, bnc = (size_t)NN * NC;
    const unsigned short* A = Abase + (size_t)z * bss;   // SP: (p, m)
    const unsigned short* B = Bbase + (size_t)z * bnc;   // V^T: (c, m)
    const int m0 = ptile * 128;
    const int n0 = ct * 128;

    __shared__ __attribute__((aligned(16))) unsigned short As[2][128 * 64];  // 32 KB
    __shared__ __attribute__((aligned(16))) unsigned short Bs[2][128 * 64];  // 32 KB

    const int t = threadIdx.x;
    const int lane = t & 63;
    const int w = t >> 6;
    const int wr = w >> 1, wc = w & 1;

    // staging: one gload round = 256 threads x 16B = 32 rows x 64 cols.
    const int sr = w * 8 + (lane >> 3);
    const int scs = ((lane & 7) ^ (lane >> 3)) * 8;   // pre-swizzled col (elems)
    const int lds_elem = w * 512;

    floatx4 acc[4][4] = {};

    auto stage = [&](int buf, int k0) {
#pragma unroll
        for (int s = 0; s < 4; ++s)
            gload_lds16(A + (size_t)(m0 + s * 32 + sr) * NN + k0 + scs,
                        &As[buf][s * 2048 + lds_elem]);
#pragma unroll
        for (int s = 0; s < 4; ++s)
            gload_lds16(B + (size_t)(n0 + s * 32 + sr) * NN + k0 + scs,
                        &Bs[buf][s * 2048 + lds_elem]);
    };

    auto compute = [&](int buf) {
#pragma unroll
        for (int kk = 0; kk < 2; ++kk) {
            bf16x8 af[4], bfr[4];
#pragma unroll
            for (int i = 0; i < 4; ++i) {
                const int ra = wr * 64 + i * 16 + (lane & 15);
                af[i] = *(const bf16x8*)(&As[buf][ra * 64 +
                        (((kk * 4 + (lane >> 4)) ^ (ra & 7)) * 8)]);
            }
#pragma unroll
            for (int jf = 0; jf < 4; ++jf) {
                const int rb = wc * 64 + jf * 16 + (lane & 15);
                bfr[jf] = *(const bf16x8*)(&Bs[buf][rb * 64 +
                        (((kk * 4 + (lane >> 4)) ^ (rb & 7)) * 8)]);
            }
#pragma unroll
            for (int i = 0; i < 4; ++i)
#pragma unroll
                for (int jf = 0; jf < 4; ++jf)
                    acc[i][jf] = __builtin_amdgcn_mfma_f32_16x16x32_bf16(
                        af[i], bfr[jf], acc[i][jf], 0, 0, 0);
        }
    };

    stage(0, 0);
    asm volatile("s_waitcnt vmcnt(0)" ::: "memory");
    __builtin_amdgcn_s_barrier();
    for (int kc = 0; kc < 63; ++kc) {
        stage((kc + 1) & 1, (kc + 1) * 64);   // prefetch next chunk (async)
        compute(kc & 1);
        asm volatile("s_waitcnt lgkmcnt(0)" ::: "memory");
        asm volatile("s_waitcnt vmcnt(0)" ::: "memory");
        __builtin_amdgcn_s_barrier();
    }
    compute(1);

    const int fr = lane >> 4;
    const int fc = lane & 15;
#pragma unroll
    for (int i = 0; i < 4; ++i) {
#pragma unroll
        for (int r = 0; r < 4; ++r) {
            int m = m0 + wr * 64 + i * 16 + fr * 4 + r;
            float linv = 1.0f / L[z * NN + m];
#pragma unroll
            for (int jf = 0; jf < 4; ++jf) {
                int n = n0 + wc * 64 + jf * 16 + fc;
                Ob[(size_t)z * bnc + (size_t)m * NC + n] = f2bf(acc[i][jf][r] * linv);
            }
        }
    }
}

// ---------------------------------------------------------------------------
extern "C" void kernel_launch(void* const* d_in, const int* in_sizes, int n_in,
                              void* d_out, int out_size, void* d_ws, size_t ws_size,
                              hipStream_t stream)
{
    const float* x     = (const float*)d_in[0];
    const float* gn_w  = (const float*)d_in[1];
    const float* gn_b  = (const float*)d_in[2];
    const float* qkv_w = (const float*)d_in[3];
    const float* qkv_b = (const float*)d_in[4];
    const float* out_w = (const float*)d_in[5];
    const float* out_b = (const float*)d_in[6];
    float* out = (float*)d_out;

    const size_t bnc = (size_t)NN * NC;          // 2,097,152 per batch
    char* w = (char*)d_ws;
    float* ss   = (float*)w;                 w += 16384;
    float* part = (float*)w;                 w += 8192;
    float* Lsum = (float*)w;                 w += (size_t)NB * NN * 4;  // row sums
    unsigned short* wq = (unsigned short*)w; w += (size_t)1536 * 512 * 2;
    unsigned short* wo = (unsigned short*)w; w += (size_t)512 * 512 * 2;
    unsigned short* qt = (unsigned short*)w; w += NB * bnc * 2;   // (b,n,c) pre-scaled
    unsigned short* kt = (unsigned short*)w; w += NB * bnc * 2;   // (b,n,c)
    unsigned short* vt = (unsigned short*)w; w += NB * bnc * 2;   // (b,c,n)
    unsigned short* SP = (unsigned short*)w; w += (size_t)NB * NN * NN * 2; // 128 MB
    // Aliases (lifetime-disjoint):
    unsigned short* ht = SP;   // ht (b,n,c) dead before MODE 2 writes SP
    unsigned short* Ob = qt;   // Ob (b,n,c) written after qt last read (MODE 2)

    hipMemsetAsync(Lsum, 0, (size_t)NB * NN * sizeof(float), stream);

    gn_partial_kernel<<<1024, 256, 0, stream>>>(x, part);
    gn_final_kernel<<<1, 128, 0, stream>>>(part, gn_w, gn_b, ss);
    wconv_kernel<<<(1536 * 512 + 512 * 512) / 256, 256, 0, stream>>>(qkv_w, out_w, wq, wo);
    htnorm_kernel<<<dim3(NN / 32, NC / 32, NB), 256, 0, stream>>>(x, ss, ht);

    // q/k: C[p,o] = ht · wqk^T   (q pre-scaled by ATTN_SCALE), PIPE=1, 2 blk/CU
    mfma_gemm<0, 128, 128, 512, 2, 1><<<dim3(1024 / 128, NN / 128, NB), 256, 0, stream>>>(
        ht, wq, qkv_b, nullptr, nullptr, qt, kt);
    // v: C[c,p] = wv · ht^T   (64x128 tile, PIPE=1, 4 blk/CU)
    mfma_gemm<1, 64, 128, 512, 4, 1><<<dim3(NN / 128, 512 / 64, NB), 256, 0, stream>>>(
        wq + (size_t)1024 * 512, ht, qkv_b, nullptr, nullptr, vt, nullptr);

    // QK^T + exp + row-sum; BM=256 wave-tile 128x64, PIPE=0, XCD-decoded
    mfma_gemm<2, 256, 128, 512, 2, 0><<<dim3(2048), 256, 0, stream>>>(
        qt, kt, nullptr, nullptr, Lsum, SP, nullptr);
    // PV + normalize; r5/r7-exact, 512 blocks, 2 blk/CU, XCD-decoded
    pv_gemm<<<dim3(512), 256, 0, stream>>>(SP, vt, Lsum, Ob);

    // out projection + bias + residual (64x128 tile, PIPE=1, 4 blk/CU)
    mfma_gemm<4, 64, 128, 512, 4, 1><<<dim3(NN / 128, 512 / 64, NB), 256, 0, stream>>>(
        wo, Ob, out_b, x, out, nullptr, nullptr);
}